// Round 1
// baseline (118.853 us; speedup 1.0000x reference)
//
#include <hip/hip_runtime.h>

// ContinuousCRF: mean-field CRF on a 96x96 grid, 3 classes, 5 iterations.
// The dense [N,N] pairwise kernel is a translation-invariant 11x11
// circular-mask convolution (radius 5, weight exp(-dist), no center tap).
// Each iteration: q = softmax(unary + Comp @ conv(q)).
//
// Round 7: 3 dispatches {2,2,1}. Mapped space so far:
//   1 coop dispatch (grid.sync):           135us  (12us/barrier)
//   2 fused dispatches (T=8, unblocked):   92-93us (halo conv LDS-bound, ~5-7us/kernel)
//   5 plain dispatches, 144 blk x 64 thr:  79.8us  (prev best; ~1.5us/node gap dominates)
//   3 dispatches, fused-2 w/ y-blocking:   this file (predict ~78us)
// Fixed harness cost ~70us (268MB ws-poison at 85% HBM peak + restore).
// Fused-2 kernel: stage 28x28 q -> conv+softmax on 18x18 (2 rows/thread,
// halves LDS reads/output) -> conv+softmax on 8x8 tile -> global.

constexpr int HH = 96, WW = 96, NN = HH * WW;
constexpr int T = 8, HALO = 5;
constexpr int EXT = T + 2 * HALO;    // 18 (single-iter halo tile)
constexpr int FEXT = T + 4 * HALO;   // 28 (fused-2 staged region)
constexpr int MEXT = T + 2 * HALO;   // 18 (fused-2 intermediate region)

// ---------------- single-iteration kernel (LAST step; proven R4 code) ----------------
template <bool FIRST, bool LAST>
__global__ __launch_bounds__(64) void crf_iter(
    const float* __restrict__ unary,   // [3][9216] planes
    const float* __restrict__ comp,    // [3][3]
    const float4* __restrict__ qin,    // q from previous iter (if !FIRST)
    float4* __restrict__ qnext,        // q out as float4 (if !LAST)
    float* __restrict__ qout)          // [3][9216] final q planes (if LAST)
{
    __shared__ float4 qs[EXT][EXT + 1];
    __shared__ float wtab[121];

    const int tid = threadIdx.x;

    for (int i = tid; i < 121; i += 64) {
        int dy = i / 11 - 5, dx = i % 11 - 5;
        int d2 = dy * dy + dx * dx;
        wtab[i] = (d2 > 0 && d2 <= 25) ? expf(-sqrtf((float)d2)) : 0.0f;
    }

    const float c00 = comp[0], c01 = comp[1], c02 = comp[2];
    const float c10 = comp[3], c11 = comp[4], c12 = comp[5];
    const float c20 = comp[6], c21 = comp[7], c22 = comp[8];

    const int bx0 = blockIdx.x * T - HALO;
    const int by0 = blockIdx.y * T - HALO;

    for (int i = tid; i < EXT * EXT; i += 64) {
        int hy = i / EXT, hx = i - hy * EXT;
        int gy = by0 + hy, gx = bx0 + hx;
        float4 q = make_float4(0.f, 0.f, 0.f, 0.f);
        if (gy >= 0 && gy < HH && gx >= 0 && gx < WW) {
            int n = gy * WW + gx;
            if (FIRST) {
                float z0 = unary[n], z1 = unary[NN + n], z2 = unary[2 * NN + n];
                float mx = fmaxf(z0, fmaxf(z1, z2));
                float e0 = expf(z0 - mx), e1 = expf(z1 - mx), e2 = expf(z2 - mx);
                float inv = 1.0f / (e0 + e1 + e2);
                q = make_float4(e0 * inv, e1 * inv, e2 * inv, 0.f);
            } else {
                q = qin[n];
            }
        }
        qs[hy][hx] = q;
    }
    __syncthreads();

    const int ty = tid >> 3, tx = tid & 7;
    float m0 = 0.f, m1 = 0.f, m2 = 0.f;
    constexpr int XLO[11] = {5, 2, 1, 1, 1, 0, 1, 1, 1, 2, 5};
    constexpr int XHI[11] = {5, 8, 9, 9, 9, 10, 9, 9, 9, 8, 5};
#pragma unroll
    for (int dyi = 0; dyi < 11; ++dyi) {
#pragma unroll
        for (int dxi = XLO[dyi]; dxi <= XHI[dyi]; ++dxi) {
            float w = wtab[dyi * 11 + dxi];
            float4 q = qs[ty + dyi][tx + dxi];
            m0 = fmaf(w, q.x, m0);
            m1 = fmaf(w, q.y, m1);
            m2 = fmaf(w, q.z, m2);
        }
    }

    float t0 = c00 * m0 + c01 * m1 + c02 * m2;
    float t1 = c10 * m0 + c11 * m1 + c12 * m2;
    float t2 = c20 * m0 + c21 * m1 + c22 * m2;

    const int n = (blockIdx.y * T + ty) * WW + (blockIdx.x * T + tx);
    float z0 = unary[n] + t0;
    float z1 = unary[NN + n] + t1;
    float z2 = unary[2 * NN + n] + t2;

    float mx = fmaxf(z0, fmaxf(z1, z2));
    float e0 = expf(z0 - mx), e1 = expf(z1 - mx), e2 = expf(z2 - mx);
    float inv = 1.0f / (e0 + e1 + e2);

    if (LAST) {
        qout[n] = e0 * inv;
        qout[NN + n] = e1 * inv;
        qout[2 * NN + n] = e2 * inv;
    } else {
        qnext[n] = make_float4(e0 * inv, e1 * inv, e2 * inv, 0.f);
    }
}

// ---------------- fused two-iteration kernel ----------------
// Stage q_in over 28x28, conv+compat+softmax -> q1 on 18x18 (in LDS),
// conv+compat+softmax -> q2 on the 8x8 tile -> global float4.
// Phase A computes 2 output rows per thread (y-register-blocking): each
// ds_read_b128 of qs0 feeds both rows, cutting LDS traffic ~1.76x vs
// unblocked; 162 active threads spread over 3 waves keeps 3 SIMDs busy.
template <bool FIRST>
__global__ __launch_bounds__(256) void crf_fused2(
    const float* __restrict__ unary,
    const float* __restrict__ comp,
    const float4* __restrict__ qin,
    float4* __restrict__ qnext)
{
    __shared__ float4 qs0[FEXT][FEXT + 1];   // 28x29 float4 = 13.0 KB
    __shared__ float4 qs1[MEXT][MEXT + 1];   // 18x19 float4 = 5.5 KB
    __shared__ float wtab[121];

    const int tid = threadIdx.x;

    if (tid < 121) {
        int dy = tid / 11 - 5, dx = tid % 11 - 5;
        int d2 = dy * dy + dx * dx;
        wtab[tid] = (d2 > 0 && d2 <= 25) ? expf(-sqrtf((float)d2)) : 0.0f;
    }

    const float c00 = comp[0], c01 = comp[1], c02 = comp[2];
    const float c10 = comp[3], c11 = comp[4], c12 = comp[5];
    const float c20 = comp[6], c21 = comp[7], c22 = comp[8];

    const int bx0 = blockIdx.x * T - 2 * HALO;
    const int by0 = blockIdx.y * T - 2 * HALO;

    // Stage q over 28x28 (zero outside image). Lanes walk contiguous sx:
    // coalesced global reads, stride-1 LDS writes.
    for (int i = tid; i < FEXT * FEXT; i += 256) {
        int sy = i / FEXT, sx = i - sy * FEXT;
        int gy = by0 + sy, gx = bx0 + sx;
        float4 q = make_float4(0.f, 0.f, 0.f, 0.f);
        if (gy >= 0 && gy < HH && gx >= 0 && gx < WW) {
            int n = gy * WW + gx;
            if (FIRST) {
                float z0 = unary[n], z1 = unary[NN + n], z2 = unary[2 * NN + n];
                float mx = fmaxf(z0, fmaxf(z1, z2));
                float e0 = expf(z0 - mx), e1 = expf(z1 - mx), e2 = expf(z2 - mx);
                float inv = 1.0f / (e0 + e1 + e2);
                q = make_float4(e0 * inv, e1 * inv, e2 * inv, 0.f);
            } else {
                q = qin[n];
            }
        }
        qs0[sy][sx] = q;
    }
    __syncthreads();

    // ---- Phase A: iteration k -> q1 on 18x18, 2 rows/thread (162 items) ----
    if (tid < (MEXT / 2) * MEXT) {
        const int iy = tid / MEXT;          // 0..8 (row pair)
        const int ix = tid - iy * MEXT;     // 0..17
        const int y1b = iy * 2, x1 = ix;

        float m00 = 0.f, m01 = 0.f, m02 = 0.f;   // output row y1b   (r=0)
        float m10 = 0.f, m11 = 0.f, m12 = 0.f;   // output row y1b+1 (r=1)

        // Input sub-row rr covers taps dyi=rr (r=0) and dyi=rr-1 (r=1).
        // dxi range = union of the circle-mask row ranges for the r's present.
        constexpr int DXLO2[12] = {5, 2, 1, 1, 1, 0, 0, 1, 1, 1, 2, 5};
        constexpr int DXHI2[12] = {5, 8, 9, 9, 9, 10, 10, 9, 9, 9, 8, 5};
#pragma unroll
        for (int rr = 0; rr < 12; ++rr) {
#pragma unroll
            for (int dxi = DXLO2[rr]; dxi <= DXHI2[rr]; ++dxi) {
                float4 q = qs0[y1b + rr][x1 + dxi];
                if (rr <= 10) {                       // compile-time after unroll
                    float w = wtab[rr * 11 + dxi];    // 0 for masked taps
                    m00 = fmaf(w, q.x, m00);
                    m01 = fmaf(w, q.y, m01);
                    m02 = fmaf(w, q.z, m02);
                }
                if (rr >= 1) {
                    float w = wtab[(rr - 1) * 11 + dxi];
                    m10 = fmaf(w, q.x, m10);
                    m11 = fmaf(w, q.y, m11);
                    m12 = fmaf(w, q.z, m12);
                }
            }
        }

#pragma unroll
        for (int r = 0; r < 2; ++r) {
            float M0 = r ? m10 : m00;
            float M1 = r ? m11 : m01;
            float M2 = r ? m12 : m02;
            int y1 = y1b + r;
            int gy = by0 + HALO + y1, gx = bx0 + HALO + x1;
            float4 q1 = make_float4(0.f, 0.f, 0.f, 0.f);
            if (gy >= 0 && gy < HH && gx >= 0 && gx < WW) {
                int n = gy * WW + gx;
                float t0 = c00 * M0 + c01 * M1 + c02 * M2;
                float t1 = c10 * M0 + c11 * M1 + c12 * M2;
                float t2 = c20 * M0 + c21 * M1 + c22 * M2;
                float z0 = unary[n] + t0;
                float z1 = unary[NN + n] + t1;
                float z2 = unary[2 * NN + n] + t2;
                float mx = fmaxf(z0, fmaxf(z1, z2));
                float e0 = expf(z0 - mx), e1 = expf(z1 - mx), e2 = expf(z2 - mx);
                float inv = 1.0f / (e0 + e1 + e2);
                q1 = make_float4(e0 * inv, e1 * inv, e2 * inv, 0.f);
            }
            qs1[y1][x1] = q1;
        }
    }
    __syncthreads();

    // ---- Phase B: iteration k+1 -> q2 on the 8x8 tile (64 threads) ----
    if (tid < 64) {
        const int ty = tid >> 3, tx = tid & 7;
        float m0 = 0.f, m1 = 0.f, m2 = 0.f;
        constexpr int XLO[11] = {5, 2, 1, 1, 1, 0, 1, 1, 1, 2, 5};
        constexpr int XHI[11] = {5, 8, 9, 9, 9, 10, 9, 9, 9, 8, 5};
#pragma unroll
        for (int dyi = 0; dyi < 11; ++dyi) {
#pragma unroll
            for (int dxi = XLO[dyi]; dxi <= XHI[dyi]; ++dxi) {
                float w = wtab[dyi * 11 + dxi];
                float4 q = qs1[ty + dyi][tx + dxi];
                m0 = fmaf(w, q.x, m0);
                m1 = fmaf(w, q.y, m1);
                m2 = fmaf(w, q.z, m2);
            }
        }
        float t0 = c00 * m0 + c01 * m1 + c02 * m2;
        float t1 = c10 * m0 + c11 * m1 + c12 * m2;
        float t2 = c20 * m0 + c21 * m1 + c22 * m2;

        const int n = (blockIdx.y * T + ty) * WW + (blockIdx.x * T + tx);
        float z0 = unary[n] + t0;
        float z1 = unary[NN + n] + t1;
        float z2 = unary[2 * NN + n] + t2;
        float mx = fmaxf(z0, fmaxf(z1, z2));
        float e0 = expf(z0 - mx), e1 = expf(z1 - mx), e2 = expf(z2 - mx);
        float inv = 1.0f / (e0 + e1 + e2);
        qnext[n] = make_float4(e0 * inv, e1 * inv, e2 * inv, 0.f);
    }
}

extern "C" void kernel_launch(void* const* d_in, const int* in_sizes, int n_in,
                              void* d_out, int out_size, void* d_ws, size_t ws_size,
                              hipStream_t stream) {
    const float* unary = (const float*)d_in[0];
    const float* comp = (const float*)d_in[1];
    float* out = (float*)d_out;

    // Ping-pong q buffers in workspace: 2 * 9216 * 16 B = 288 KiB.
    float4* qA = (float4*)d_ws;
    float4* qB = qA + NN;

    dim3 grid(WW / T, HH / T);    // 12x12 = 144 blocks

    // iters 1+2 fused, iters 3+4 fused, iter 5 single (writes planes).
    crf_fused2<true ><<<grid, dim3(256), 0, stream>>>(unary, comp, nullptr, qA);
    crf_fused2<false><<<grid, dim3(256), 0, stream>>>(unary, comp, qA, qB);
    crf_iter<false, true><<<grid, dim3(64), 0, stream>>>(unary, comp, qB, nullptr, out);
}

// Round 2
// 94.678 us; speedup vs baseline: 1.2553x; 1.2553x over previous
//
#include <hip/hip_runtime.h>

// ContinuousCRF: mean-field CRF on a 96x96 grid, 3 classes, 5 iterations.
// The dense [N,N] pairwise kernel is a translation-invariant 11x11
// circular-mask convolution (radius 5, weight exp(-dist), no center tap).
// Each iteration: q = softmax(unary + Comp @ conv(q)).
//
// Round 8: 3 dispatches {2,2,1}, spill-fixed fused kernel. Map so far:
//   1 coop dispatch (grid.sync):           135us  (12us/barrier)
//   2 fused dispatches (T=8, unblocked):   92-93us
//   5 plain dispatches, 144 blk x 64 thr:  79.8us  (proven fallback)
//   3 dispatches, fused-2, SPILLED:        118.9us (VGPR=256, 20MB scratch/disp)
// R1 post-mortem: phase A's ~116 fully-unrolled ds_read_b128 let the
// scheduler hoist reads past the 256-VGPR addressing cap -> scratch spill
// (WRITE_SIZE 12.5MB/disp, 42us/kernel, VALUBusy 2.7%). Fix: sched_barrier(0)
// after each conv row caps live float4s at ~12 -> ~80 VGPR, no spill.
// Fixed harness cost ~70us (268MB ws-poison at 85% HBM peak + restore).

constexpr int HH = 96, WW = 96, NN = HH * WW;
constexpr int T = 8, HALO = 5;
constexpr int EXT = T + 2 * HALO;    // 18 (single-iter halo tile)
constexpr int FEXT = T + 4 * HALO;   // 28 (fused-2 staged region)
constexpr int MEXT = T + 2 * HALO;   // 18 (fused-2 intermediate region)

// ---------------- single-iteration kernel (LAST step; proven R4 code) ----------------
template <bool FIRST, bool LAST>
__global__ __launch_bounds__(64) void crf_iter(
    const float* __restrict__ unary,   // [3][9216] planes
    const float* __restrict__ comp,    // [3][3]
    const float4* __restrict__ qin,    // q from previous iter (if !FIRST)
    float4* __restrict__ qnext,        // q out as float4 (if !LAST)
    float* __restrict__ qout)          // [3][9216] final q planes (if LAST)
{
    __shared__ float4 qs[EXT][EXT + 1];
    __shared__ float wtab[121];

    const int tid = threadIdx.x;

    for (int i = tid; i < 121; i += 64) {
        int dy = i / 11 - 5, dx = i % 11 - 5;
        int d2 = dy * dy + dx * dx;
        wtab[i] = (d2 > 0 && d2 <= 25) ? expf(-sqrtf((float)d2)) : 0.0f;
    }

    const float c00 = comp[0], c01 = comp[1], c02 = comp[2];
    const float c10 = comp[3], c11 = comp[4], c12 = comp[5];
    const float c20 = comp[6], c21 = comp[7], c22 = comp[8];

    const int bx0 = blockIdx.x * T - HALO;
    const int by0 = blockIdx.y * T - HALO;

    for (int i = tid; i < EXT * EXT; i += 64) {
        int hy = i / EXT, hx = i - hy * EXT;
        int gy = by0 + hy, gx = bx0 + hx;
        float4 q = make_float4(0.f, 0.f, 0.f, 0.f);
        if (gy >= 0 && gy < HH && gx >= 0 && gx < WW) {
            int n = gy * WW + gx;
            if (FIRST) {
                float z0 = unary[n], z1 = unary[NN + n], z2 = unary[2 * NN + n];
                float mx = fmaxf(z0, fmaxf(z1, z2));
                float e0 = expf(z0 - mx), e1 = expf(z1 - mx), e2 = expf(z2 - mx);
                float inv = 1.0f / (e0 + e1 + e2);
                q = make_float4(e0 * inv, e1 * inv, e2 * inv, 0.f);
            } else {
                q = qin[n];
            }
        }
        qs[hy][hx] = q;
    }
    __syncthreads();

    const int ty = tid >> 3, tx = tid & 7;
    float m0 = 0.f, m1 = 0.f, m2 = 0.f;
    constexpr int XLO[11] = {5, 2, 1, 1, 1, 0, 1, 1, 1, 2, 5};
    constexpr int XHI[11] = {5, 8, 9, 9, 9, 10, 9, 9, 9, 8, 5};
#pragma unroll
    for (int dyi = 0; dyi < 11; ++dyi) {
#pragma unroll
        for (int dxi = XLO[dyi]; dxi <= XHI[dyi]; ++dxi) {
            float w = wtab[dyi * 11 + dxi];
            float4 q = qs[ty + dyi][tx + dxi];
            m0 = fmaf(w, q.x, m0);
            m1 = fmaf(w, q.y, m1);
            m2 = fmaf(w, q.z, m2);
        }
    }

    float t0 = c00 * m0 + c01 * m1 + c02 * m2;
    float t1 = c10 * m0 + c11 * m1 + c12 * m2;
    float t2 = c20 * m0 + c21 * m1 + c22 * m2;

    const int n = (blockIdx.y * T + ty) * WW + (blockIdx.x * T + tx);
    float z0 = unary[n] + t0;
    float z1 = unary[NN + n] + t1;
    float z2 = unary[2 * NN + n] + t2;

    float mx = fmaxf(z0, fmaxf(z1, z2));
    float e0 = expf(z0 - mx), e1 = expf(z1 - mx), e2 = expf(z2 - mx);
    float inv = 1.0f / (e0 + e1 + e2);

    if (LAST) {
        qout[n] = e0 * inv;
        qout[NN + n] = e1 * inv;
        qout[2 * NN + n] = e2 * inv;
    } else {
        qnext[n] = make_float4(e0 * inv, e1 * inv, e2 * inv, 0.f);
    }
}

// ---------------- fused two-iteration kernel ----------------
// Stage q_in over 28x28, conv+compat+softmax -> q1 on 18x18 (in LDS),
// conv+compat+softmax -> q2 on the 8x8 tile -> global float4.
// Phase A computes 2 output rows per thread (y-register-blocking): each
// ds_read_b128 of qs0 feeds both rows (92 reads / 2 outputs vs 81 / 1).
// sched_barrier(0) per row caps live float4s (R1 spilled without it).
template <bool FIRST>
__global__ __launch_bounds__(256) void crf_fused2(
    const float* __restrict__ unary,
    const float* __restrict__ comp,
    const float4* __restrict__ qin,
    float4* __restrict__ qnext)
{
    __shared__ float4 qs0[FEXT][FEXT + 1];   // 28x29 float4 = 13.0 KB
    __shared__ float4 qs1[MEXT][MEXT + 1];   // 18x19 float4 = 5.5 KB
    __shared__ float wtab[121];

    const int tid = threadIdx.x;

    if (tid < 121) {
        int dy = tid / 11 - 5, dx = tid % 11 - 5;
        int d2 = dy * dy + dx * dx;
        wtab[tid] = (d2 > 0 && d2 <= 25) ? expf(-sqrtf((float)d2)) : 0.0f;
    }

    const float c00 = comp[0], c01 = comp[1], c02 = comp[2];
    const float c10 = comp[3], c11 = comp[4], c12 = comp[5];
    const float c20 = comp[6], c21 = comp[7], c22 = comp[8];

    const int bx0 = blockIdx.x * T - 2 * HALO;
    const int by0 = blockIdx.y * T - 2 * HALO;

    // Stage q over 28x28 (zero outside image). Lanes walk contiguous sx:
    // coalesced global reads, stride-1 LDS writes.
    for (int i = tid; i < FEXT * FEXT; i += 256) {
        int sy = i / FEXT, sx = i - sy * FEXT;
        int gy = by0 + sy, gx = bx0 + sx;
        float4 q = make_float4(0.f, 0.f, 0.f, 0.f);
        if (gy >= 0 && gy < HH && gx >= 0 && gx < WW) {
            int n = gy * WW + gx;
            if (FIRST) {
                float z0 = unary[n], z1 = unary[NN + n], z2 = unary[2 * NN + n];
                float mx = fmaxf(z0, fmaxf(z1, z2));
                float e0 = expf(z0 - mx), e1 = expf(z1 - mx), e2 = expf(z2 - mx);
                float inv = 1.0f / (e0 + e1 + e2);
                q = make_float4(e0 * inv, e1 * inv, e2 * inv, 0.f);
            } else {
                q = qin[n];
            }
        }
        qs0[sy][sx] = q;
    }
    __syncthreads();

    // ---- Phase A: iteration k -> q1 on 18x18, 2 rows/thread (162 items) ----
    if (tid < (MEXT / 2) * MEXT) {
        const int iy = tid / MEXT;          // 0..8 (row pair)
        const int ix = tid - iy * MEXT;     // 0..17
        const int y1b = iy * 2, x1 = ix;

        float m00 = 0.f, m01 = 0.f, m02 = 0.f;   // output row y1b   (r=0)
        float m10 = 0.f, m11 = 0.f, m12 = 0.f;   // output row y1b+1 (r=1)

        // Input sub-row rr covers taps dyi=rr (r=0) and dyi=rr-1 (r=1).
        // dxi range = union of the circle-mask row ranges for the r's present.
        constexpr int DXLO2[12] = {5, 2, 1, 1, 1, 0, 0, 1, 1, 1, 2, 5};
        constexpr int DXHI2[12] = {5, 8, 9, 9, 9, 10, 10, 9, 9, 9, 8, 5};
#pragma unroll
        for (int rr = 0; rr < 12; ++rr) {
#pragma unroll
            for (int dxi = DXLO2[rr]; dxi <= DXHI2[rr]; ++dxi) {
                float4 q = qs0[y1b + rr][x1 + dxi];
                if (rr <= 10) {                       // compile-time after unroll
                    float w = wtab[rr * 11 + dxi];    // 0 for masked taps
                    m00 = fmaf(w, q.x, m00);
                    m01 = fmaf(w, q.y, m01);
                    m02 = fmaf(w, q.z, m02);
                }
                if (rr >= 1) {
                    float w = wtab[(rr - 1) * 11 + dxi];
                    m10 = fmaf(w, q.x, m10);
                    m11 = fmaf(w, q.y, m11);
                    m12 = fmaf(w, q.z, m12);
                }
            }
            // R1 spilled to scratch (VGPR=256, 12.5MB WRITE_SIZE/dispatch):
            // the scheduler hoisted ~116 float4 LDS reads. Fence each row so
            // at most ~12 float4s are live -> ~80 VGPR, zero spill.
            __builtin_amdgcn_sched_barrier(0);
        }

#pragma unroll
        for (int r = 0; r < 2; ++r) {
            float M0 = r ? m10 : m00;
            float M1 = r ? m11 : m01;
            float M2 = r ? m12 : m02;
            int y1 = y1b + r;
            int gy = by0 + HALO + y1, gx = bx0 + HALO + x1;
            float4 q1 = make_float4(0.f, 0.f, 0.f, 0.f);
            if (gy >= 0 && gy < HH && gx >= 0 && gx < WW) {
                int n = gy * WW + gx;
                float t0 = c00 * M0 + c01 * M1 + c02 * M2;
                float t1 = c10 * M0 + c11 * M1 + c12 * M2;
                float t2 = c20 * M0 + c21 * M1 + c22 * M2;
                float z0 = unary[n] + t0;
                float z1 = unary[NN + n] + t1;
                float z2 = unary[2 * NN + n] + t2;
                float mx = fmaxf(z0, fmaxf(z1, z2));
                float e0 = expf(z0 - mx), e1 = expf(z1 - mx), e2 = expf(z2 - mx);
                float inv = 1.0f / (e0 + e1 + e2);
                q1 = make_float4(e0 * inv, e1 * inv, e2 * inv, 0.f);
            }
            qs1[y1][x1] = q1;
        }
    }
    __syncthreads();

    // ---- Phase B: iteration k+1 -> q2 on the 8x8 tile (64 threads) ----
    // Identical structure to crf_iter's conv (proven no-spill at ~0.5us);
    // __syncthreads keeps its reads from co-scheduling with phase A, so no
    // fences here (it needs the hoisting for latency hiding: 1 active wave).
    if (tid < 64) {
        const int ty = tid >> 3, tx = tid & 7;
        float m0 = 0.f, m1 = 0.f, m2 = 0.f;
        constexpr int XLO[11] = {5, 2, 1, 1, 1, 0, 1, 1, 1, 2, 5};
        constexpr int XHI[11] = {5, 8, 9, 9, 9, 10, 9, 9, 9, 8, 5};
#pragma unroll
        for (int dyi = 0; dyi < 11; ++dyi) {
#pragma unroll
            for (int dxi = XLO[dyi]; dxi <= XHI[dyi]; ++dxi) {
                float w = wtab[dyi * 11 + dxi];
                float4 q = qs1[ty + dyi][tx + dxi];
                m0 = fmaf(w, q.x, m0);
                m1 = fmaf(w, q.y, m1);
                m2 = fmaf(w, q.z, m2);
            }
        }
        float t0 = c00 * m0 + c01 * m1 + c02 * m2;
        float t1 = c10 * m0 + c11 * m1 + c12 * m2;
        float t2 = c20 * m0 + c21 * m1 + c22 * m2;

        const int n = (blockIdx.y * T + ty) * WW + (blockIdx.x * T + tx);
        float z0 = unary[n] + t0;
        float z1 = unary[NN + n] + t1;
        float z2 = unary[2 * NN + n] + t2;
        float mx = fmaxf(z0, fmaxf(z1, z2));
        float e0 = expf(z0 - mx), e1 = expf(z1 - mx), e2 = expf(z2 - mx);
        float inv = 1.0f / (e0 + e1 + e2);
        qnext[n] = make_float4(e0 * inv, e1 * inv, e2 * inv, 0.f);
    }
}

extern "C" void kernel_launch(void* const* d_in, const int* in_sizes, int n_in,
                              void* d_out, int out_size, void* d_ws, size_t ws_size,
                              hipStream_t stream) {
    const float* unary = (const float*)d_in[0];
    const float* comp = (const float*)d_in[1];
    float* out = (float*)d_out;

    // Ping-pong q buffers in workspace: 2 * 9216 * 16 B = 288 KiB.
    float4* qA = (float4*)d_ws;
    float4* qB = qA + NN;

    dim3 grid(WW / T, HH / T);    // 12x12 = 144 blocks

    // iters 1+2 fused, iters 3+4 fused, iter 5 single (writes planes).
    crf_fused2<true ><<<grid, dim3(256), 0, stream>>>(unary, comp, nullptr, qA);
    crf_fused2<false><<<grid, dim3(256), 0, stream>>>(unary, comp, qA, qB);
    crf_iter<false, true><<<grid, dim3(64), 0, stream>>>(unary, comp, qB, nullptr, out);
}

// Round 3
// 73.330 us; speedup vs baseline: 1.6208x; 1.2911x over previous
//
#include <hip/hip_runtime.h>

// ContinuousCRF: mean-field CRF on a 96x96 grid, 3 classes, 5 iterations.
// The dense [N,N] pairwise kernel is a translation-invariant 11x11
// circular-mask convolution (radius 5, weight exp(-dist), no center tap).
// Each iteration: q = softmax(unary + Comp @ conv(q)).
//
// Round 9: 3 dispatches {2,2,1}, spill-free by construction. Map so far:
//   1 coop dispatch (grid.sync):           135us  (12us/barrier)
//   5 plain dispatches, 144 blk x 64 thr:  79.8us  (proven fallback)
//   3 disp fused-2, unfenced:              118.9us (VGPR=256, 20MB scratch/disp)
//   3 disp fused-2, phase-A fenced:        94.7us  (VGPR=256, 10MB scratch: phase B
//                                                   + per-tap wtab LDS reads still hoist)
// R2 post-mortem: every conv tap was TWO LDS ops (ds_read_b32 weight +
// ds_read_b128 q); phase B was unfenced. Fix: (1) the 11x11 kernel has only
// 13 distinct weights -> compute once into VGPRs (same expf(-sqrtf(d2)) bits,
// zero-taps skipped at compile time = exact), (2) sched_barrier(0) per conv
// row in ALL phases. Live set ~12 float4 -> ~100 VGPR, no scratch.
// Fixed harness cost ~70us (268MB ws-poison at 85% HBM peak + restore).

constexpr int HH = 96, WW = 96, NN = HH * WW;
constexpr int T = 8, HALO = 5;
constexpr int EXT = T + 2 * HALO;    // 18 (single-iter halo tile)
constexpr int FEXT = T + 4 * HALO;   // 28 (fused-2 staged region)
constexpr int MEXT = T + 2 * HALO;   // 18 (fused-2 intermediate region)

// 13 distinct squared distances with nonzero weight in the radius-5 circle.
__device__ __forceinline__ int slotOf(int d2) {
    const int D2S[13] = {1, 2, 4, 5, 8, 9, 10, 13, 16, 17, 18, 20, 25};
    int s = 0;
#pragma unroll
    for (int k = 0; k < 13; ++k)
        if (D2S[k] == d2) s = k;
    return s;   // callers guarantee d2 is in the set (compile-time folded)
}

// Per-thread weight registers; expf(-sqrtf(d2)) exactly as the LDS table did.
#define INIT_WV(wv)                                            \
    float wv[13];                                              \
    {                                                          \
        const int D2S[13] = {1, 2, 4, 5, 8, 9, 10, 13, 16, 17, 18, 20, 25}; \
        _Pragma("unroll")                                      \
        for (int k = 0; k < 13; ++k)                           \
            wv[k] = expf(-sqrtf((float)D2S[k]));               \
    }

// ---------------- single-iteration kernel (LAST step) ----------------
template <bool FIRST, bool LAST>
__global__ __launch_bounds__(64) void crf_iter(
    const float* __restrict__ unary,   // [3][9216] planes
    const float* __restrict__ comp,    // [3][3]
    const float4* __restrict__ qin,    // q from previous iter (if !FIRST)
    float4* __restrict__ qnext,        // q out as float4 (if !LAST)
    float* __restrict__ qout)          // [3][9216] final q planes (if LAST)
{
    __shared__ float4 qs[EXT][EXT + 1];

    const int tid = threadIdx.x;
    INIT_WV(wv)

    const float c00 = comp[0], c01 = comp[1], c02 = comp[2];
    const float c10 = comp[3], c11 = comp[4], c12 = comp[5];
    const float c20 = comp[6], c21 = comp[7], c22 = comp[8];

    const int bx0 = blockIdx.x * T - HALO;
    const int by0 = blockIdx.y * T - HALO;

    for (int i = tid; i < EXT * EXT; i += 64) {
        int hy = i / EXT, hx = i - hy * EXT;
        int gy = by0 + hy, gx = bx0 + hx;
        float4 q = make_float4(0.f, 0.f, 0.f, 0.f);
        if (gy >= 0 && gy < HH && gx >= 0 && gx < WW) {
            int n = gy * WW + gx;
            if (FIRST) {
                float z0 = unary[n], z1 = unary[NN + n], z2 = unary[2 * NN + n];
                float mx = fmaxf(z0, fmaxf(z1, z2));
                float e0 = expf(z0 - mx), e1 = expf(z1 - mx), e2 = expf(z2 - mx);
                float inv = 1.0f / (e0 + e1 + e2);
                q = make_float4(e0 * inv, e1 * inv, e2 * inv, 0.f);
            } else {
                q = qin[n];
            }
        }
        qs[hy][hx] = q;
    }
    __syncthreads();

    const int ty = tid >> 3, tx = tid & 7;
    float m0 = 0.f, m1 = 0.f, m2 = 0.f;
#pragma unroll
    for (int dyi = 0; dyi < 11; ++dyi) {
#pragma unroll
        for (int dxi = 0; dxi < 11; ++dxi) {
            const int d2 = (dyi - 5) * (dyi - 5) + (dxi - 5) * (dxi - 5);
            if (d2 > 0 && d2 <= 25) {          // compile-time circle mask
                float w = wv[slotOf(d2)];      // folds to a register
                float4 q = qs[ty + dyi][tx + dxi];
                m0 = fmaf(w, q.x, m0);
                m1 = fmaf(w, q.y, m1);
                m2 = fmaf(w, q.z, m2);
            }
        }
        __builtin_amdgcn_sched_barrier(0);     // cap live float4s per row
    }

    float t0 = c00 * m0 + c01 * m1 + c02 * m2;
    float t1 = c10 * m0 + c11 * m1 + c12 * m2;
    float t2 = c20 * m0 + c21 * m1 + c22 * m2;

    const int n = (blockIdx.y * T + ty) * WW + (blockIdx.x * T + tx);
    float z0 = unary[n] + t0;
    float z1 = unary[NN + n] + t1;
    float z2 = unary[2 * NN + n] + t2;

    float mx = fmaxf(z0, fmaxf(z1, z2));
    float e0 = expf(z0 - mx), e1 = expf(z1 - mx), e2 = expf(z2 - mx);
    float inv = 1.0f / (e0 + e1 + e2);

    if (LAST) {
        qout[n] = e0 * inv;
        qout[NN + n] = e1 * inv;
        qout[2 * NN + n] = e2 * inv;
    } else {
        qnext[n] = make_float4(e0 * inv, e1 * inv, e2 * inv, 0.f);
    }
}

// ---------------- fused two-iteration kernel ----------------
// Stage q_in over 28x28, conv+compat+softmax -> q1 on 18x18 (in LDS),
// conv+compat+softmax -> q2 on the 8x8 tile -> global float4.
// Phase A: 2 output rows per thread; each ds_read_b128 feeds both rows.
// All conv rows fenced with sched_barrier(0) (R1/R2 spilled without).
template <bool FIRST>
__global__ __launch_bounds__(256) void crf_fused2(
    const float* __restrict__ unary,
    const float* __restrict__ comp,
    const float4* __restrict__ qin,
    float4* __restrict__ qnext)
{
    __shared__ float4 qs0[FEXT][FEXT + 1];   // 28x29 float4 = 13.0 KB
    __shared__ float4 qs1[MEXT][MEXT + 1];   // 18x19 float4 = 5.5 KB

    const int tid = threadIdx.x;
    INIT_WV(wv)

    const float c00 = comp[0], c01 = comp[1], c02 = comp[2];
    const float c10 = comp[3], c11 = comp[4], c12 = comp[5];
    const float c20 = comp[6], c21 = comp[7], c22 = comp[8];

    const int bx0 = blockIdx.x * T - 2 * HALO;
    const int by0 = blockIdx.y * T - 2 * HALO;

    // Stage q over 28x28 (zero outside image). Coalesced global reads,
    // stride-1 LDS writes.
    for (int i = tid; i < FEXT * FEXT; i += 256) {
        int sy = i / FEXT, sx = i - sy * FEXT;
        int gy = by0 + sy, gx = bx0 + sx;
        float4 q = make_float4(0.f, 0.f, 0.f, 0.f);
        if (gy >= 0 && gy < HH && gx >= 0 && gx < WW) {
            int n = gy * WW + gx;
            if (FIRST) {
                float z0 = unary[n], z1 = unary[NN + n], z2 = unary[2 * NN + n];
                float mx = fmaxf(z0, fmaxf(z1, z2));
                float e0 = expf(z0 - mx), e1 = expf(z1 - mx), e2 = expf(z2 - mx);
                float inv = 1.0f / (e0 + e1 + e2);
                q = make_float4(e0 * inv, e1 * inv, e2 * inv, 0.f);
            } else {
                q = qin[n];
            }
        }
        qs0[sy][sx] = q;
    }
    __syncthreads();

    // ---- Phase A: iteration k -> q1 on 18x18, 2 rows/thread (162 items) ----
    if (tid < (MEXT / 2) * MEXT) {
        const int iy = tid / MEXT;          // 0..8 (row pair)
        const int ix = tid - iy * MEXT;     // 0..17
        const int y1b = iy * 2, x1 = ix;

        float m00 = 0.f, m01 = 0.f, m02 = 0.f;   // output row y1b   (r=0)
        float m10 = 0.f, m11 = 0.f, m12 = 0.f;   // output row y1b+1 (r=1)

        // Input sub-row rr feeds tap dyi=rr of output r=0 and dyi=rr-1 of r=1.
#pragma unroll
        for (int rr = 0; rr < 12; ++rr) {
#pragma unroll
            for (int dxi = 0; dxi < 11; ++dxi) {
                const int dA = (rr - 5) * (rr - 5) + (dxi - 5) * (dxi - 5);
                const int dB = (rr - 6) * (rr - 6) + (dxi - 5) * (dxi - 5);
                const bool g0 = (rr <= 10) && dA > 0 && dA <= 25;
                const bool g1 = (rr >= 1) && dB > 0 && dB <= 25;
                if (g0 || g1) {                       // compile-time
                    float4 q = qs0[y1b + rr][x1 + dxi];
                    if (g0) {
                        float w = wv[slotOf(dA)];
                        m00 = fmaf(w, q.x, m00);
                        m01 = fmaf(w, q.y, m01);
                        m02 = fmaf(w, q.z, m02);
                    }
                    if (g1) {
                        float w = wv[slotOf(dB)];
                        m10 = fmaf(w, q.x, m10);
                        m11 = fmaf(w, q.y, m11);
                        m12 = fmaf(w, q.z, m12);
                    }
                }
            }
            __builtin_amdgcn_sched_barrier(0);   // cap live float4s per row
        }

#pragma unroll
        for (int r = 0; r < 2; ++r) {
            float M0 = r ? m10 : m00;
            float M1 = r ? m11 : m01;
            float M2 = r ? m12 : m02;
            int y1 = y1b + r;
            int gy = by0 + HALO + y1, gx = bx0 + HALO + x1;
            float4 q1 = make_float4(0.f, 0.f, 0.f, 0.f);
            if (gy >= 0 && gy < HH && gx >= 0 && gx < WW) {
                int n = gy * WW + gx;
                float t0 = c00 * M0 + c01 * M1 + c02 * M2;
                float t1 = c10 * M0 + c11 * M1 + c12 * M2;
                float t2 = c20 * M0 + c21 * M1 + c22 * M2;
                float z0 = unary[n] + t0;
                float z1 = unary[NN + n] + t1;
                float z2 = unary[2 * NN + n] + t2;
                float mx = fmaxf(z0, fmaxf(z1, z2));
                float e0 = expf(z0 - mx), e1 = expf(z1 - mx), e2 = expf(z2 - mx);
                float inv = 1.0f / (e0 + e1 + e2);
                q1 = make_float4(e0 * inv, e1 * inv, e2 * inv, 0.f);
            }
            qs1[y1][x1] = q1;
        }
    }
    __syncthreads();

    // ---- Phase B: iteration k+1 -> q2 on the 8x8 tile (64 threads) ----
    if (tid < 64) {
        const int ty = tid >> 3, tx = tid & 7;
        float m0 = 0.f, m1 = 0.f, m2 = 0.f;
#pragma unroll
        for (int dyi = 0; dyi < 11; ++dyi) {
#pragma unroll
            for (int dxi = 0; dxi < 11; ++dxi) {
                const int d2 = (dyi - 5) * (dyi - 5) + (dxi - 5) * (dxi - 5);
                if (d2 > 0 && d2 <= 25) {
                    float w = wv[slotOf(d2)];
                    float4 q = qs1[ty + dyi][tx + dxi];
                    m0 = fmaf(w, q.x, m0);
                    m1 = fmaf(w, q.y, m1);
                    m2 = fmaf(w, q.z, m2);
                }
            }
            __builtin_amdgcn_sched_barrier(0);   // R2: unfenced phase B spilled
        }
        float t0 = c00 * m0 + c01 * m1 + c02 * m2;
        float t1 = c10 * m0 + c11 * m1 + c12 * m2;
        float t2 = c20 * m0 + c21 * m1 + c22 * m2;

        const int n = (blockIdx.y * T + ty) * WW + (blockIdx.x * T + tx);
        float z0 = unary[n] + t0;
        float z1 = unary[NN + n] + t1;
        float z2 = unary[2 * NN + n] + t2;
        float mx = fmaxf(z0, fmaxf(z1, z2));
        float e0 = expf(z0 - mx), e1 = expf(z1 - mx), e2 = expf(z2 - mx);
        float inv = 1.0f / (e0 + e1 + e2);
        qnext[n] = make_float4(e0 * inv, e1 * inv, e2 * inv, 0.f);
    }
}

extern "C" void kernel_launch(void* const* d_in, const int* in_sizes, int n_in,
                              void* d_out, int out_size, void* d_ws, size_t ws_size,
                              hipStream_t stream) {
    const float* unary = (const float*)d_in[0];
    const float* comp = (const float*)d_in[1];
    float* out = (float*)d_out;

    // Ping-pong q buffers in workspace: 2 * 9216 * 16 B = 288 KiB.
    float4* qA = (float4*)d_ws;
    float4* qB = qA + NN;

    dim3 grid(WW / T, HH / T);    // 12x12 = 144 blocks

    // iters 1+2 fused, iters 3+4 fused, iter 5 single (writes planes).
    crf_fused2<true ><<<grid, dim3(256), 0, stream>>>(unary, comp, nullptr, qA);
    crf_fused2<false><<<grid, dim3(256), 0, stream>>>(unary, comp, qA, qB);
    crf_iter<false, true><<<grid, dim3(64), 0, stream>>>(unary, comp, qB, nullptr, out);
}